// Round 1
// 991.191 us; speedup vs baseline: 1.1178x; 1.1178x over previous
//
#include <hip/hip_runtime.h>
#include <hip/hip_bf16.h>

#define T_TOK 8192
#define HDIM  1024
#define IDIM  4096
#define NEXP  8
#define BK    64
#define BUFSZ 49152   // one pipeline stage: 48 KB (A + B tiles)

typedef __bf16 bf16x8 __attribute__((ext_vector_type(8)));
typedef float  f32x4  __attribute__((ext_vector_type(4)));

typedef __attribute__((address_space(3))) unsigned int       lds_u32;
typedef const __attribute__((address_space(1))) unsigned int glb_u32;

__device__ __forceinline__ void gld16(void* lds, const void* g) {
    // async global->LDS, 16B per lane; LDS dest = wave-uniform base + lane*16
    __builtin_amdgcn_global_load_lds((glb_u32*)g, (lds_u32*)lds, 16, 0, 0);
}

// raw barrier (no implicit vmcnt(0) drain) with compiler fences
#define BAR() do { asm volatile("" ::: "memory"); __builtin_amdgcn_s_barrier(); asm volatile("" ::: "memory"); } while (0)
#define WAITV6() asm volatile("s_waitcnt vmcnt(6)" ::: "memory")
#define WAITV0() asm volatile("s_waitcnt vmcnt(0)" ::: "memory")

// swizzled fragment read from a [rows][64] bf16 tile (128B rows).
// logical byte off = ks*64 + fq*16; stored with byte ^= (row&7)<<4
__device__ __forceinline__ bf16x8 ldfrag(const char* base, int row, int ks, int fq) {
    int boff = (((ks << 6) | (fq << 4)) ^ ((row & 7) << 4));
    return *(const bf16x8*)(base + (row << 7) + boff);
}

// ---------------- hs fp32 -> bf16 ------------------------------------------
__global__ __launch_bounds__(256) void convert_hs_kernel(
    const float* __restrict__ hs, __bf16* __restrict__ hsb)
{
    size_t i = ((size_t)blockIdx.x * 256 + threadIdx.x) * 8;
    float4 a = *(const float4*)(hs + i);
    float4 b = *(const float4*)(hs + i + 4);
    bf16x8 v;
    v[0] = (__bf16)a.x; v[1] = (__bf16)a.y; v[2] = (__bf16)a.z; v[3] = (__bf16)a.w;
    v[4] = (__bf16)b.x; v[5] = (__bf16)b.y; v[6] = (__bf16)b.z; v[7] = (__bf16)b.w;
    *(bf16x8*)(hsb + i) = v;
}

// ---------------- weights fp32 [K][N] -> bf16 [N][K] (per expert) ----------
__global__ __launch_bounds__(256) void transpose_w_kernel(
    const float* __restrict__ gw, const float* __restrict__ uw,
    const float* __restrict__ dw,
    __bf16* __restrict__ Gt, __bf16* __restrict__ Ut, __bf16* __restrict__ Dt)
{
    const int z = blockIdx.y, mat = z >> 3, e = z & 7;
    const float* src; __bf16* dst; int R, C;
    if (mat == 0)      { src = gw; dst = Gt; R = HDIM; C = IDIM; }
    else if (mat == 1) { src = uw; dst = Ut; R = HDIM; C = IDIM; }
    else               { src = dw; dst = Dt; R = IDIM; C = HDIM; }
    src += (size_t)e * HDIM * IDIM;
    dst += (size_t)e * HDIM * IDIM;

    const int tilesC = C >> 6;
    const int tx = blockIdx.x % tilesC, ty = blockIdx.x / tilesC;
    const int r0 = ty * 64, c0 = tx * 64;

    __shared__ __bf16 Lt[64][72];   // [c][r], pad 72 -> 16B-aligned rows

    const int tr  = threadIdx.x >> 4;         // 0..15
    const int tc4 = (threadIdx.x & 15) * 4;   // 0..60
#pragma unroll
    for (int p = 0; p < 4; ++p) {
        int r = p * 16 + tr;
        float4 v = *(const float4*)(src + (size_t)(r0 + r) * C + c0 + tc4);
        Lt[tc4 + 0][r] = (__bf16)v.x;
        Lt[tc4 + 1][r] = (__bf16)v.y;
        Lt[tc4 + 2][r] = (__bf16)v.z;
        Lt[tc4 + 3][r] = (__bf16)v.w;
    }
    __syncthreads();

    const int oc  = threadIdx.x >> 3;         // 0..31
    const int or8 = (threadIdx.x & 7) * 8;    // 0..56
#pragma unroll
    for (int p = 0; p < 2; ++p) {
        int c = oc + p * 32;
        bf16x8 v = *(const bf16x8*)(&Lt[c][or8]);
        *(bf16x8*)(dst + (size_t)(c0 + c) * R + r0 + or8) = v;
    }
}

// ---------------- router: fp64 logits, top-2, no atomics --------------------
__global__ __launch_bounds__(256) void router_kernel(
    const float* __restrict__ hs, const float* __restrict__ gpw,
    int* __restrict__ ca, int* __restrict__ cb,
    float* __restrict__ wa, float* __restrict__ wb)
{
    const int wv = threadIdx.x >> 6, lane = threadIdx.x & 63;
    const int t  = blockIdx.x * 4 + wv;
    const float* hrow = hs + (size_t)t * HDIM;

    double acc[NEXP];
#pragma unroll
    for (int e = 0; e < NEXP; ++e) acc[e] = 0.0;

#pragma unroll
    for (int it = 0; it < HDIM / 64; ++it) {
        int i = lane + it * 64;
        double x = (double)hrow[i];
#pragma unroll
        for (int e = 0; e < NEXP; ++e)
            acc[e] += x * (double)gpw[e * HDIM + i];
    }
#pragma unroll
    for (int e = 0; e < NEXP; ++e)
#pragma unroll
        for (int m = 32; m > 0; m >>= 1)
            acc[e] += __shfl_xor(acc[e], m);

    if (lane == 0) {
        int a = 0;
#pragma unroll
        for (int e = 1; e < NEXP; ++e) if (acc[e] > acc[a]) a = e;
        int b = (a == 0) ? 1 : 0;
#pragma unroll
        for (int e = 0; e < NEXP; ++e) if (e != a && acc[e] > acc[b]) b = e;
        double wA = 1.0 / (1.0 + exp(acc[b] - acc[a]));  // = p_a/(p_a+p_b)
        ca[t] = a; cb[t] = b;
        wa[t] = (float)wA; wb[t] = (float)(1.0 - wA);
    }
}

// ---------------- build per-expert lists (deterministic scan) ---------------
__global__ __launch_bounds__(256) void build_lists_kernel(
    const int* __restrict__ ca, const int* __restrict__ cb,
    const float* __restrict__ wa, const float* __restrict__ wb,
    int* __restrict__ lists, float* __restrict__ wlists, int* __restrict__ counts)
{
    const int e = blockIdx.x;
    const int tid = threadIdx.x, wv = tid >> 6, lane = tid & 63;
    __shared__ int wsum[4];
    int base = 0;
    for (int t0 = 0; t0 < T_TOK; t0 += 256) {
        int t  = t0 + tid;
        int m2 = (cb[t] == e);
        int m  = (ca[t] == e) | m2;
        unsigned long long bal = __ballot(m);
        int my   = __popcll(bal & ((1ull << lane) - 1ull));
        if (lane == 0) wsum[wv] = __popcll(bal);
        __syncthreads();
        int off = 0;
        for (int w2 = 0; w2 < wv; ++w2) off += wsum[w2];
        int tot = wsum[0] + wsum[1] + wsum[2] + wsum[3];
        if (m) {
            int pos = base + off + my;
            lists[e * T_TOK + pos]  = t * 2 + m2;
            wlists[e * T_TOK + pos] = m2 ? wb[t] : wa[t];
        }
        base += tot;
        __syncthreads();
    }
    if (tid == 0) counts[e] = base;
}

// ---------------- FFN1: h = silu(x@G)*(x@U) --------------------------------
// 128(tok) x (128 G-cols + 128 U-cols) tile, BK=64, 512 thr (8 waves, 2Mx4N),
// 3-deep LDS pipeline (3x48KB), counted vmcnt(6), XOR-swizzled LDS, setprio.
__global__ __launch_bounds__(512, 2) void ffn1_kernel(
    const __bf16* __restrict__ hsb, const __bf16* __restrict__ Gt,
    const __bf16* __restrict__ Ut, const int* __restrict__ counts,
    const int* __restrict__ lists, __bf16* __restrict__ hbuf)
{
    const int e   = blockIdx.z;
    const int cnt = counts[e];
    const int m0  = blockIdx.y * 128;
    if (m0 >= cnt) return;
    const int n0  = blockIdx.x * 128;
    const int tid = threadIdx.x;
    const int wv  = tid >> 6, lane = tid & 63;

    extern __shared__ char sm[];
    int* toks = (int*)(sm + 3 * BUFSZ);

    if (tid < 128) {
        int idx = m0 + tid;
        toks[tid] = lists[e * T_TOK + (idx < cnt ? idx : 0)];
    }
    __syncthreads();

    // staging: each 8KB part = 64 rows x 128B; thread covers (rl, seg=lane&7)
    const int rl = (wv << 3) + (lane >> 3);          // row within 64-row chunk
    const int ce = (((lane & 7) ^ (rl & 7)) << 3);   // pre-swizzled col (elems)
    const __bf16* Ge = Gt + (size_t)e * IDIM * HDIM;
    const __bf16* Ue = Ut + (size_t)e * IDIM * HDIM;
    const __bf16* sA[2]; const __bf16* sG[2]; const __bf16* sU[2];
#pragma unroll
    for (int c = 0; c < 2; ++c) {
        sA[c] = hsb + (size_t)(toks[(c << 6) + rl] >> 1) * HDIM + ce;
        sG[c] = Ge + (size_t)(n0 + (c << 6) + rl) * HDIM + ce;
        sU[c] = Ue + (size_t)(n0 + (c << 6) + rl) * HDIM + ce;
    }
    char* wbase = sm + (wv << 10);   // wave slice inside each 8KB part

    // prologue: stage tiles 0 -> buf0, 1 -> buf1 (6 issues each)
#pragma unroll
    for (int t = 0; t < 2; ++t) {
        char* b = wbase + t * BUFSZ;
        const size_t off = (size_t)t * BK;
        gld16(b,          sA[0] + off); gld16(b + 8192,  sA[1] + off);
        gld16(b + 16384,  sG[0] + off); gld16(b + 24576, sG[1] + off);
        gld16(b + 32768,  sU[0] + off); gld16(b + 40960, sU[1] + off);
    }
    WAITV6(); BAR();   // tile0 resident, tile1 in flight

    const int wr = wv >> 2, wc = wv & 3;         // 2M x 4N wave grid
    const int fr = lane & 15, fq = lane >> 4;
    const int ar0 = (wr << 6) + fr;
    const int br0 = (wc << 5) + fr;

    f32x4 accg[4][2], accu[4][2];
#pragma unroll
    for (int i = 0; i < 4; ++i)
#pragma unroll
        for (int j = 0; j < 2; ++j) { accg[i][j] = (f32x4)0.0f; accu[i][j] = (f32x4)0.0f; }

    int cur = 0, stg = 2;
    const int NT = HDIM / BK;  // 16
    for (int kt = 0; kt < NT; ++kt) {
        const char* bufA = sm + cur * BUFSZ;
        const char* bufG = bufA + 16384;
        const char* bufU = bufA + 32768;
        char* nb = wbase + stg * BUFSZ;
        const size_t off = (size_t)(kt + 2) * BK;
        const bool pf = (kt + 2) < NT;

        // ---- phase 1: G ----
        if (pf) { gld16(nb, sA[0]+off); gld16(nb+8192, sA[1]+off); gld16(nb+16384, sG[0]+off); }
        bf16x8 a[4][2], bg[2][2];
#pragma unroll
        for (int mi = 0; mi < 4; ++mi)
#pragma unroll
            for (int ks = 0; ks < 2; ++ks)
                a[mi][ks] = ldfrag(bufA, ar0 + mi * 16, ks, fq);
#pragma unroll
        for (int ni = 0; ni < 2; ++ni)
#pragma unroll
            for (int ks = 0; ks < 2; ++ks)
                bg[ni][ks] = ldfrag(bufG, br0 + ni * 16, ks, fq);
        __builtin_amdgcn_s_setprio(1);
#pragma unroll
        for (int mi = 0; mi < 4; ++mi)
#pragma unroll
            for (int ni = 0; ni < 2; ++ni)
#pragma unroll
                for (int ks = 0; ks < 2; ++ks)
                    accg[mi][ni] = __builtin_amdgcn_mfma_f32_16x16x32_bf16(a[mi][ks], bg[ni][ks], accg[mi][ni], 0, 0, 0);
        __builtin_amdgcn_s_setprio(0);
        BAR();

        // ---- phase 2: U (A frags reused) ----
        if (pf) { gld16(nb+24576, sG[1]+off); gld16(nb+32768, sU[0]+off); gld16(nb+40960, sU[1]+off); }
        bf16x8 bu[2][2];
#pragma unroll
        for (int ni = 0; ni < 2; ++ni)
#pragma unroll
            for (int ks = 0; ks < 2; ++ks)
                bu[ni][ks] = ldfrag(bufU, br0 + ni * 16, ks, fq);
        __builtin_amdgcn_s_setprio(1);
#pragma unroll
        for (int mi = 0; mi < 4; ++mi)
#pragma unroll
            for (int ni = 0; ni < 2; ++ni)
#pragma unroll
                for (int ks = 0; ks < 2; ++ks)
                    accu[mi][ni] = __builtin_amdgcn_mfma_f32_16x16x32_bf16(a[mi][ks], bu[ni][ks], accu[mi][ni], 0, 0, 0);
        __builtin_amdgcn_s_setprio(0);

        if (kt < NT - 1) {
            if (kt + 2 < NT) { WAITV6(); } else { WAITV0(); }
            BAR();
        }
        cur = (cur == 2) ? 0 : cur + 1;
        stg = (stg == 2) ? 0 : stg + 1;
    }

#pragma unroll
    for (int mi = 0; mi < 4; ++mi)
#pragma unroll
        for (int r = 0; r < 4; ++r) {
            int row = (wr << 6) + mi * 16 + fq * 4 + r;
            if (m0 + row < cnt) {
                __bf16* dst = hbuf + (size_t)toks[row] * IDIM + n0 + (wc << 5) + fr;
#pragma unroll
                for (int ni = 0; ni < 2; ++ni) {
                    float g = accg[mi][ni][r], u = accu[mi][ni][r];
                    float h = g * (1.0f / (1.0f + __expf(-g))) * u;
                    dst[ni * 16] = (__bf16)h;
                }
            }
        }
}

// ---------------- FFN2: out[tok] += w * (h @ Dt) ----------------------------
// 256(tok) x 128 tile, BK=64, 512 thr (8 waves, 4Mx2N), same 3-deep pipeline.
__global__ __launch_bounds__(512, 2) void ffn2_kernel(
    const __bf16* __restrict__ hbuf, const __bf16* __restrict__ Dt,
    const int* __restrict__ counts, const int* __restrict__ lists,
    const float* __restrict__ wlists, float* __restrict__ out)
{
    const int e   = blockIdx.z;
    const int cnt = counts[e];
    const int m0  = blockIdx.y * 256;
    if (m0 >= cnt) return;
    const int n0  = blockIdx.x * 128;
    const int tid = threadIdx.x;
    const int wv  = tid >> 6, lane = tid & 63;

    extern __shared__ char sm[];
    int*   toks = (int*)(sm + 3 * BUFSZ);
    float* wts  = (float*)(sm + 3 * BUFSZ + 1024);

    if (tid < 256) {
        int idx  = m0 + tid;
        int cidx = idx < cnt ? idx : 0;
        toks[tid] = lists[e * T_TOK + cidx];
        wts[tid]  = wlists[e * T_TOK + cidx];
    }
    __syncthreads();

    const int rl = (wv << 3) + (lane >> 3);
    const int ce = (((lane & 7) ^ (rl & 7)) << 3);
    const __bf16* De = Dt + (size_t)e * HDIM * IDIM;
    const __bf16* sA[4]; const __bf16* sB[2];
#pragma unroll
    for (int c = 0; c < 4; ++c)
        sA[c] = hbuf + (size_t)toks[(c << 6) + rl] * IDIM + ce;
#pragma unroll
    for (int c = 0; c < 2; ++c)
        sB[c] = De + (size_t)(n0 + (c << 6) + rl) * IDIM + ce;
    char* wbase = sm + (wv << 10);

#pragma unroll
    for (int t = 0; t < 2; ++t) {
        char* b = wbase + t * BUFSZ;
        const size_t off = (size_t)t * BK;
        gld16(b,          sA[0] + off); gld16(b + 8192,  sA[1] + off);
        gld16(b + 16384,  sA[2] + off); gld16(b + 24576, sA[3] + off);
        gld16(b + 32768,  sB[0] + off); gld16(b + 40960, sB[1] + off);
    }
    WAITV6(); BAR();

    const int wr = wv >> 1, wc = wv & 1;         // 4M x 2N wave grid
    const int fr = lane & 15, fq = lane >> 4;
    const int ar0 = (wr << 6) + fr;
    const int br0 = (wc << 6) + fr;

    f32x4 acc[4][4];
#pragma unroll
    for (int i = 0; i < 4; ++i)
#pragma unroll
        for (int j = 0; j < 4; ++j) acc[i][j] = (f32x4)0.0f;

    int cur = 0, stg = 2;
    const int NT = IDIM / BK;  // 64
    for (int kt = 0; kt < NT; ++kt) {
        const char* bufA = sm + cur * BUFSZ;
        const char* bufB = bufA + 32768;
        char* nb = wbase + stg * BUFSZ;
        const size_t off = (size_t)(kt + 2) * BK;
        const bool pf = (kt + 2) < NT;

        // ---- phase 1: n-cols 0..31 of wave ----
        if (pf) { gld16(nb, sA[0]+off); gld16(nb+8192, sA[1]+off); gld16(nb+16384, sA[2]+off); }
        bf16x8 a[4][2], b0[2][2];
#pragma unroll
        for (int mi = 0; mi < 4; ++mi)
#pragma unroll
            for (int ks = 0; ks < 2; ++ks)
                a[mi][ks] = ldfrag(bufA, ar0 + mi * 16, ks, fq);
#pragma unroll
        for (int ni = 0; ni < 2; ++ni)
#pragma unroll
            for (int ks = 0; ks < 2; ++ks)
                b0[ni][ks] = ldfrag(bufB, br0 + ni * 16, ks, fq);
        __builtin_amdgcn_s_setprio(1);
#pragma unroll
        for (int mi = 0; mi < 4; ++mi)
#pragma unroll
            for (int ni = 0; ni < 2; ++ni)
#pragma unroll
                for (int ks = 0; ks < 2; ++ks)
                    acc[mi][ni] = __builtin_amdgcn_mfma_f32_16x16x32_bf16(a[mi][ks], b0[ni][ks], acc[mi][ni], 0, 0, 0);
        __builtin_amdgcn_s_setprio(0);
        BAR();

        // ---- phase 2: n-cols 32..63 (A frags reused) ----
        if (pf) { gld16(nb+24576, sA[3]+off); gld16(nb+32768, sB[0]+off); gld16(nb+40960, sB[1]+off); }
        bf16x8 b1[2][2];
#pragma unroll
        for (int ni = 0; ni < 2; ++ni)
#pragma unroll
            for (int ks = 0; ks < 2; ++ks)
                b1[ni][ks] = ldfrag(bufB, br0 + 32 + ni * 16, ks, fq);
        __builtin_amdgcn_s_setprio(1);
#pragma unroll
        for (int mi = 0; mi < 4; ++mi)
#pragma unroll
            for (int ni = 0; ni < 2; ++ni)
#pragma unroll
                for (int ks = 0; ks < 2; ++ks)
                    acc[mi][ni + 2] = __builtin_amdgcn_mfma_f32_16x16x32_bf16(a[mi][ks], b1[ni][ks], acc[mi][ni + 2], 0, 0, 0);
        __builtin_amdgcn_s_setprio(0);

        if (kt < NT - 1) {
            if (kt + 2 < NT) { WAITV6(); } else { WAITV0(); }
            BAR();
        }
        cur = (cur == 2) ? 0 : cur + 1;
        stg = (stg == 2) ? 0 : stg + 1;
    }

#pragma unroll
    for (int mi = 0; mi < 4; ++mi)
#pragma unroll
        for (int r = 0; r < 4; ++r) {
            int row = (wr << 6) + mi * 16 + fq * 4 + r;
            if (m0 + row < cnt) {
                int   tok = toks[row] >> 1;
                float w   = wts[row];
                float* dst = out + (size_t)tok * HDIM + n0 + (wc << 6) + fr;
#pragma unroll
                for (int ni = 0; ni < 4; ++ni)
                    atomicAdd(&dst[ni * 16], w * acc[mi][ni][r]);
            }
        }
}

// ---------------------------------------------------------------------------
extern "C" void kernel_launch(void* const* d_in, const int* in_sizes, int n_in,
                              void* d_out, int out_size, void* d_ws, size_t ws_size,
                              hipStream_t stream)
{
    const float* hs  = (const float*)d_in[0];
    const float* gpw = (const float*)d_in[1];
    const float* gw  = (const float*)d_in[2];
    const float* uw  = (const float*)d_in[3];
    const float* dw  = (const float*)d_in[4];
    float* out = (float*)d_out;

    char* p = (char*)d_ws;
    __bf16* hsb  = (__bf16*)p;  p += (size_t)T_TOK * HDIM * 2;            // 16 MB
    __bf16* Gt   = (__bf16*)p;  p += (size_t)NEXP * IDIM * HDIM * 2;      // 64 MB
    __bf16* Ut   = (__bf16*)p;  p += (size_t)NEXP * IDIM * HDIM * 2;      // 64 MB
    __bf16* Dt   = (__bf16*)p;  p += (size_t)NEXP * HDIM * IDIM * 2;      // 64 MB
    __bf16* hbuf = (__bf16*)p;  p += (size_t)2 * T_TOK * IDIM * 2;        // 128 MB
    int*    lists  = (int*)p;   p += (size_t)NEXP * T_TOK * 4;
    float*  wlists = (float*)p; p += (size_t)NEXP * T_TOK * 4;
    int*    ca = (int*)p;       p += (size_t)T_TOK * 4;
    int*    cb = (int*)p;       p += (size_t)T_TOK * 4;
    float*  wa = (float*)p;     p += (size_t)T_TOK * 4;
    float*  wb = (float*)p;     p += (size_t)T_TOK * 4;
    int*    counts = (int*)p;

    static bool attr_set = false;
    if (!attr_set) {
        (void)hipFuncSetAttribute((const void*)ffn1_kernel,
                                  hipFuncAttributeMaxDynamicSharedMemorySize, 149504);
        (void)hipFuncSetAttribute((const void*)ffn2_kernel,
                                  hipFuncAttributeMaxDynamicSharedMemorySize, 149504);
        attr_set = true;
    }

    hipMemsetAsync(out, 0, (size_t)T_TOK * HDIM * sizeof(float), stream);

    convert_hs_kernel<<<T_TOK * HDIM / 2048, 256, 0, stream>>>(hs, hsb);
    transpose_w_kernel<<<dim3(1024, 24), 256, 0, stream>>>(gw, uw, dw, Gt, Ut, Dt);
    router_kernel<<<T_TOK / 4, 256, 0, stream>>>(hs, gpw, ca, cb, wa, wb);
    build_lists_kernel<<<NEXP, 256, 0, stream>>>(ca, cb, wa, wb, lists, wlists, counts);

    // FFN1: 128-token x (128G+128U) tiles, 3-stage pipelined, 146KB dynamic LDS
    ffn1_kernel<<<dim3(IDIM / 128, T_TOK / 128, NEXP), 512, 3 * BUFSZ + 512, stream>>>(
        hsb, Gt, Ut, counts, lists, hbuf);
    // FFN2: 256-token x 128 tiles
    ffn2_kernel<<<dim3(HDIM / 128, T_TOK / 256, NEXP), 512, 3 * BUFSZ + 2048, stream>>>(
        hbuf, Dt, counts, lists, wlists, out);
}